// Round 6
// baseline (262.146 us; speedup 1.0000x reference)
//
#include <hip/hip_runtime.h>
#include <hip/hip_bf16.h>

// out[b,o,n] = sum_{k<19,c<64} x[b,c,neigh[n,k]] * W[o,k*64+c] + bias[o]
// B=4, N_VERTS=40962, K_RING=19, C=64.
//
// R14: MSHR theory. All rounds pin gather throughput at ~5 TB/s =
// (~55 outstanding 64B lines/CU) x 64B / latency: a per-CU miss-
// concurrency wall, not BW (R13b: FETCH 105->23MB, time unchanged) and
// not occupancy/pipelining (VGPR counts show pipelines were intact).
// R13b failed because its per-wave W stream (780MB, 12M L1-missing
// lines) consumed ~2/3 of the miss slots, cancelling the L2-residency
// latency win. R14 removes W from the VMEM path: 16/19 rings of the
// kc-half W staged to LDS ONCE per block (single barrier, no recurring
// drains), rings 16-18 in prologue-prefetched regs. Gathers marked nt
// (zero reuse; keep L1 for W/neigh). kc-split XCD pinning kept (proven
// resident). prep_kernel = transpose + convw merged (one less launch).

#define NV   40962
#define KR   19
#define CIN  64
#define COUT 64
#define NB   4
#define NTILES 321   // ceil(NV/128)
#define TBLK 641     // transpose blocks per batch (ceil(NV/64))

typedef __bf16 bf16;
typedef __bf16 bf16x8 __attribute__((ext_vector_type(8)));
typedef float  floatx4 __attribute__((ext_vector_type(4)));

#define XT_ELEMS ((size_t)NB * NV * CIN)               // also = NB*COUT*NV
#define WB_OFF   ((XT_ELEMS * 2 + 255) & ~(size_t)255)
#define WF_BYTES ((size_t)COUT * KR * CIN * 2)
#define P1_OFF   ((WB_OFF + WF_BYTES + 255) & ~(size_t)255)
#define WS_SPLIT (P1_OFF + XT_ELEMS * 2)               // ~42.1 MB
#define WS_MID   (WB_OFF + WF_BYTES)                   // ~21.2 MB

// ---------------------------------------------------------------------------
// prep_kernel: blocks [0, NB*TBLK) transpose x (B,C,N) fp32 ->
// xt2[b][kc][v][32ch] bf16 (64B line per vertex row); blocks
// [NB*TBLK, +38) convert W fp32 -> bf16 MFMA A-fragments, kc-major:
//   frag F = (kc*KR + ring)*4 + ot; lane L holds 8 bf16:
//   Wf[(F*64+L)*8 + j] = W[ot*16 + (L&15)][ring*64 + kc*32 + (L>>4)*8 + j]
// ---------------------------------------------------------------------------
__global__ __launch_bounds__(256) void prep_kernel(
    const float* __restrict__ x, const float* __restrict__ W,
    bf16* __restrict__ xt, bf16* __restrict__ Wf)
{
    __shared__ float tile[64 * 65];
    const int bid = blockIdx.x;
    const int t   = threadIdx.x;

    if (bid < NB * TBLK) {
        const int b  = bid / TBLK;
        const int v0 = (bid - b * TBLK) * 64;

        if (v0 + 64 <= NV) {
            #pragma unroll
            for (int r = 0; r < 4; ++r) {
                int flat = r * 256 + t;
                int c    = flat >> 4;
                int v4   = (flat & 15) * 4;
                floatx4 val = *(const floatx4*)&x[((size_t)(b * CIN + c)) * NV + v0 + v4];
                tile[(v4 + 0) * 65 + c] = val.x;
                tile[(v4 + 1) * 65 + c] = val.y;
                tile[(v4 + 2) * 65 + c] = val.z;
                tile[(v4 + 3) * 65 + c] = val.w;
            }
        } else {
            const int vl = t & 63;
            const int c0 = t >> 6;
            const int vg = min(v0 + vl, NV - 1);
            #pragma unroll
            for (int p = 0; p < 16; ++p) {
                int c = c0 * 16 + p;
                tile[vl * 65 + c] = x[((size_t)(b * CIN + c)) * NV + vg];
            }
        }
        __syncthreads();

        const int v = t >> 2;
        const int q = t & 3;
        if (v0 + v < NV) {
            #pragma unroll
            for (int p = 0; p < 2; ++p) {
                int chunk = q + p * 4;              // 8 channels
                bf16x8 o;
                #pragma unroll
                for (int j = 0; j < 8; ++j)
                    o[j] = (bf16)tile[v * 65 + chunk * 8 + j];
                int kc = chunk >> 2;
                size_t dst = ((size_t)((b * 2 + kc) * NV + v0 + v)) * 32 + (chunk & 3) * 8;
                __builtin_nontemporal_store(o, (bf16x8*)&xt[dst]);
            }
        }
    } else {
        const int idx = (bid - NB * TBLK) * 256 + t;
        if (idx < 2 * KR * 4 * 64) {
            const int lane = idx & 63;
            const int ot   = (idx >> 6) & 3;
            const int q    = idx >> 8;             // kc*KR + ring
            const int kc   = (q >= KR) ? 1 : 0;
            const int ring = q - kc * KR;
            const int row  = ot * 16 + (lane & 15);
            const int col0 = ring * 64 + kc * 32 + (lane >> 4) * 8;
            const float* src = W + (size_t)row * (KR * CIN) + col0;
            floatx4 a = *(const floatx4*)(src);
            floatx4 c = *(const floatx4*)(src + 4);
            bf16x8 o;
            o[0] = (bf16)a.x; o[1] = (bf16)a.y; o[2] = (bf16)a.z; o[3] = (bf16)a.w;
            o[4] = (bf16)c.x; o[5] = (bf16)c.y; o[6] = (bf16)c.z; o[7] = (bf16)c.w;
            *(bf16x8*)(Wf + (size_t)idx * 8) = o;
        }
    }
}

// ---------------------------------------------------------------------------
// conv_split_kernel: kc-split gather-GEMM, W in LDS.
// Block (b,kc,tile); slice = b*2+kc -> XCD (L2-resident 2.6MB xt slice).
// W rings 0..15 staged to LDS once (64KB, 2 blocks/CU); rings 16..18 in
// prologue-prefetched registers. Loop has NO barriers: per ring r, issue
// idx r+3 + nt gather r+2, ds_read 4 W frags, 8 MFMA. Gathers are the
// only recurring VMEM -> full miss-queue concurrency for them.
// ---------------------------------------------------------------------------
__global__ __launch_bounds__(256, 2) void conv_split_kernel(
    const int*   __restrict__ neigh,
    const bf16*  __restrict__ xt,     // [b][kc][v][32] bf16
    const bf16*  __restrict__ Wf,     // kc-major fragments
    const float* __restrict__ bias,
    float*       __restrict__ out,    // (B, 64, NV) fp32
    bf16*        __restrict__ P1)     // (B, 64, NV) bf16 partial (kc=1)
{
    __shared__ bf16 Wl[16 * 2048];                 // 64KB: rings 0..15

    const int i     = blockIdx.x;
    const int slice = i & 7;                       // -> XCD
    const int b     = slice >> 1;
    const int kc    = slice & 1;
    const int tile  = i >> 3;                      // 0..320

    const int t    = threadIdx.x;
    const int wv   = t >> 6;
    const int lane = t & 63;
    const int l15  = lane & 15;
    const int g    = lane >> 4;

    const bf16* wsrc = Wf + (size_t)kc * (KR * 2048);   // elems

    // ---- stage W rings 0..15 -> LDS (once)
    #pragma unroll
    for (int ii = 0; ii < 16; ++ii) {
        int e = (ii * 256 + t) * 8;
        *(bf16x8*)&Wl[e] = *(const bf16x8*)&wsrc[e];
    }

    const int n0 = tile * 128 + wv * 32;
    int nn[2], ib[2];
    #pragma unroll
    for (int s = 0; s < 2; ++s) {
        nn[s] = n0 + s * 16 + l15;
        ib[s] = min(nn[s], NV - 1) * KR;
    }

    const bf16* xb = xt + ((size_t)slice * NV) * 32 + g * 8;   // + v*32

    floatx4 acc[2][4];
    #pragma unroll
    for (int s = 0; s < 2; ++s)
        #pragma unroll
        for (int o = 0; o < 4; ++o)
            acc[s][o] = (floatx4){0.f, 0.f, 0.f, 0.f};

    // ---- prologue: W rings 16..18 -> regs; idx rings 0,1,2; gathers 0,1
    bf16x8 wtail[3][4];
    #pragma unroll
    for (int rr = 0; rr < 3; ++rr)
        #pragma unroll
        for (int ot = 0; ot < 4; ++ot)
            wtail[rr][ot] = *(const bf16x8*)(wsrc + ((16 + rr) * 4 + ot) * 512 + lane * 8);

    int inxt[2], i3rd[2];
    bf16x8 xf[2], xg[2];
    #pragma unroll
    for (int s = 0; s < 2; ++s) {
        int v0i = neigh[ib[s] + 0];
        inxt[s] = neigh[ib[s] + 1];
        i3rd[s] = neigh[ib[s] + 2];
        int v = ((unsigned)v0i < (unsigned)NV) ? v0i : 0;
        xf[s] = __builtin_nontemporal_load((const bf16x8*)(xb + (size_t)v * 32));
    }
    #pragma unroll
    for (int s = 0; s < 2; ++s) {
        int v = ((unsigned)inxt[s] < (unsigned)NV) ? inxt[s] : 0;
        xg[s] = __builtin_nontemporal_load((const bf16x8*)(xb + (size_t)v * 32));
    }

    __syncthreads();   // one-time: W staging visible (drains prologue, ok)

    #pragma unroll
    for (int r = 0; r < KR; ++r) {
        int inew[2];
        bf16x8 xh[2];

        if (r + 3 < KR) {
            #pragma unroll
            for (int s = 0; s < 2; ++s)
                inew[s] = neigh[ib[s] + r + 3];
        }
        if (r + 2 < KR) {
            #pragma unroll
            for (int s = 0; s < 2; ++s) {
                int v = ((unsigned)i3rd[s] < (unsigned)NV) ? i3rd[s] : 0;
                xh[s] = __builtin_nontemporal_load((const bf16x8*)(xb + (size_t)v * 32));
            }
        }

        // ---- W frags for ring r (LDS or tail regs; r is compile-time)
        bf16x8 wf[4];
        if (r < 16) {
            #pragma unroll
            for (int ot = 0; ot < 4; ++ot)
                wf[ot] = *(const bf16x8*)&Wl[(r * 4 + ot) * 512 + lane * 8];
        } else {
            #pragma unroll
            for (int ot = 0; ot < 4; ++ot)
                wf[ot] = wtail[r - 16][ot];
        }

        __builtin_amdgcn_s_setprio(1);
        #pragma unroll
        for (int ot = 0; ot < 4; ++ot)
            #pragma unroll
            for (int s = 0; s < 2; ++s)
                acc[s][ot] = __builtin_amdgcn_mfma_f32_16x16x32_bf16(
                    wf[ot], xf[s], acc[s][ot], 0, 0, 0);
        __builtin_amdgcn_s_setprio(0);

        // rotate (SSA-renamed under full unroll)
        if (r + 1 < KR) {
            #pragma unroll
            for (int s = 0; s < 2; ++s) xf[s] = xg[s];
        }
        if (r + 2 < KR) {
            #pragma unroll
            for (int s = 0; s < 2; ++s) {
                xg[s] = xh[s];
                inxt[s] = i3rd[s];
                i3rd[s] = (r + 3 < KR) ? inew[s] : 0;
            }
        }
    }

    // ---- epilogue: C/D col=l15 (vertex), row=g*4+ii (output)
    if (kc == 0) {
        #pragma unroll
        for (int ot = 0; ot < 4; ++ot) {
            #pragma unroll
            for (int ii = 0; ii < 4; ++ii) {
                const int o = ot * 16 + g * 4 + ii;
                const float bv = bias[o];
                #pragma unroll
                for (int s = 0; s < 2; ++s) {
                    if (nn[s] < NV)
                        __builtin_nontemporal_store(acc[s][ot][ii] + bv,
                            &out[((size_t)(b * COUT + o)) * NV + nn[s]]);
                }
            }
        }
    } else {
        #pragma unroll
        for (int ot = 0; ot < 4; ++ot) {
            #pragma unroll
            for (int ii = 0; ii < 4; ++ii) {
                const int o = ot * 16 + g * 4 + ii;
                #pragma unroll
                for (int s = 0; s < 2; ++s) {
                    if (nn[s] < NV)
                        __builtin_nontemporal_store((bf16)acc[s][ot][ii],
                            &P1[((size_t)(b * COUT + o)) * NV + nn[s]]);
                }
            }
        }
    }
}

// ---------------------------------------------------------------------------
// reduce_kernel: out += P1 (bf16). Pure streaming, nt.
// ---------------------------------------------------------------------------
__global__ __launch_bounds__(256) void reduce_kernel(
    float* __restrict__ out, const bf16* __restrict__ P1)
{
    const size_t total8 = XT_ELEMS / 8;
    for (size_t j = (size_t)blockIdx.x * 256 + threadIdx.x; j < total8;
         j += (size_t)gridDim.x * 256) {
        bf16x8 p = __builtin_nontemporal_load((const bf16x8*)P1 + j);
        floatx4* op = (floatx4*)out + j * 2;
        floatx4 a = __builtin_nontemporal_load(op);
        floatx4 c = __builtin_nontemporal_load(op + 1);
        a.x += (float)p[0]; a.y += (float)p[1]; a.z += (float)p[2]; a.w += (float)p[3];
        c.x += (float)p[4]; c.y += (float)p[5]; c.z += (float)p[6]; c.w += (float)p[7];
        __builtin_nontemporal_store(a, op);
        __builtin_nontemporal_store(c, op + 1);
    }
}

// ---------------------------------------------------------------------------
// Mid fallback (ws fits old budget only): both kc in-block, direct out.
// ---------------------------------------------------------------------------
__global__ __launch_bounds__(256, 3) void conv_nosplit_kernel(
    const int*   __restrict__ neigh,
    const bf16*  __restrict__ xt,
    const bf16*  __restrict__ Wf,
    const float* __restrict__ bias,
    float*       __restrict__ out)
{
    const int i    = blockIdx.x;
    const int b    = (i & 7) >> 1;
    const int tile = (i >> 3) * 2 + (i & 1);
    if (tile >= NTILES) return;

    const int t    = threadIdx.x;
    const int wv   = t >> 6;
    const int lane = t & 63;
    const int l15  = lane & 15;
    const int g    = lane >> 4;

    const int n0 = tile * 128 + wv * 32;
    int nn[2], ib[2];
    #pragma unroll
    for (int s = 0; s < 2; ++s) {
        nn[s] = n0 + s * 16 + l15;
        ib[s] = min(nn[s], NV - 1) * KR;
    }

    const bf16* xb0 = xt + ((size_t)(b * 2 + 0) * NV) * 32 + g * 8;
    const bf16* xb1 = xt + ((size_t)(b * 2 + 1) * NV) * 32 + g * 8;
    const bf16* wb  = Wf + lane * 8;

    floatx4 acc[2][4];
    #pragma unroll
    for (int s = 0; s < 2; ++s)
        #pragma unroll
        for (int o = 0; o < 4; ++o)
            acc[s][o] = (floatx4){0.f, 0.f, 0.f, 0.f};

    int inxt[2];
    bf16x8 xf[2][2], wf[2][4];
    #pragma unroll
    for (int s = 0; s < 2; ++s) {
        int v0i = neigh[ib[s] + 0];
        inxt[s] = neigh[ib[s] + 1];
        int v = ((unsigned)v0i < (unsigned)NV) ? v0i : 0;
        xf[s][0] = *(const bf16x8*)(xb0 + (size_t)v * 32);
        xf[s][1] = *(const bf16x8*)(xb1 + (size_t)v * 32);
    }
    #pragma unroll
    for (int kc = 0; kc < 2; ++kc)
        #pragma unroll
        for (int f = 0; f < 4; ++f)
            wf[kc][f] = *(const bf16x8*)(wb + (size_t)kc * (KR * 2048) + f * 512);

    #pragma unroll
    for (int r = 0; r < KR; ++r) {
        int inew[2];
        bf16x8 wg[2][4], xg[2][2];
        if (r + 2 < KR) {
            #pragma unroll
            for (int s = 0; s < 2; ++s) inew[s] = neigh[ib[s] + r + 2];
        }
        if (r + 1 < KR) {
            #pragma unroll
            for (int kc = 0; kc < 2; ++kc)
                #pragma unroll
                for (int f = 0; f < 4; ++f)
                    wg[kc][f] = *(const bf16x8*)(wb + (size_t)kc * (KR * 2048)
                                                 + (size_t)(r + 1) * 2048 + f * 512);
            #pragma unroll
            for (int s = 0; s < 2; ++s) {
                int v = ((unsigned)inxt[s] < (unsigned)NV) ? inxt[s] : 0;
                xg[s][0] = *(const bf16x8*)(xb0 + (size_t)v * 32);
                xg[s][1] = *(const bf16x8*)(xb1 + (size_t)v * 32);
            }
        }

        __builtin_amdgcn_s_setprio(1);
        #pragma unroll
        for (int kc = 0; kc < 2; ++kc)
            #pragma unroll
            for (int ot = 0; ot < 4; ++ot)
                #pragma unroll
                for (int s = 0; s < 2; ++s)
                    acc[s][ot] = __builtin_amdgcn_mfma_f32_16x16x32_bf16(
                        wf[kc][ot], xf[s][kc], acc[s][ot], 0, 0, 0);
        __builtin_amdgcn_s_setprio(0);

        if (r + 1 < KR) {
            #pragma unroll
            for (int s = 0; s < 2; ++s) {
                xf[s][0] = xg[s][0];
                xf[s][1] = xg[s][1];
                inxt[s]  = (r + 2 < KR) ? inew[s] : 0;
            }
            #pragma unroll
            for (int kc = 0; kc < 2; ++kc)
                #pragma unroll
                for (int f = 0; f < 4; ++f)
                    wf[kc][f] = wg[kc][f];
        }
    }

    #pragma unroll
    for (int ot = 0; ot < 4; ++ot) {
        #pragma unroll
        for (int ii = 0; ii < 4; ++ii) {
            const int o = ot * 16 + g * 4 + ii;
            const float bv = bias[o];
            #pragma unroll
            for (int s = 0; s < 2; ++s) {
                if (nn[s] < NV)
                    out[((size_t)(b * COUT + o)) * NV + nn[s]] = acc[s][ot][ii] + bv;
            }
        }
    }
}

// ---------------------------------------------------------------------------
// Last-resort fallback (no workspace).
// ---------------------------------------------------------------------------
__global__ __launch_bounds__(64) void fallback_kernel(
    const int*   __restrict__ neigh,
    const float* __restrict__ x,
    const float* __restrict__ W,
    const float* __restrict__ bias,
    float*       __restrict__ out)
{
    __shared__ float xg[KR * CIN];
    const int bn = blockIdx.x;
    const int b  = bn / NV;
    const int n  = bn % NV;
    const int t  = threadIdx.x;

    for (int k = t; k < KR * CIN; k += 64) {
        int r = k / CIN, c = k - r * CIN;
        int v = neigh[n * KR + r];
        v = ((unsigned)v < (unsigned)NV) ? v : 0;
        xg[k] = x[((size_t)(b * CIN + c)) * NV + v];
    }
    __syncthreads();

    float s = bias[t];
    const float* wrow = W + (size_t)t * (KR * CIN);
    for (int k = 0; k < KR * CIN; ++k) s += xg[k] * wrow[k];
    out[((size_t)(b * COUT + t)) * NV + n] = s;
}

// ---------------------------------------------------------------------------
extern "C" void kernel_launch(void* const* d_in, const int* in_sizes, int n_in,
                              void* d_out, int out_size, void* d_ws, size_t ws_size,
                              hipStream_t stream)
{
    const float* x     = (const float*)d_in[0];
    const int*   neigh = (const int*)d_in[1];
    const float* W     = (const float*)d_in[2];
    const float* bias  = (const float*)d_in[3];
    float* out = (float*)d_out;

    if (d_ws != nullptr && ws_size >= WS_MID) {
        bf16* xt = (bf16*)d_ws;
        bf16* Wf = (bf16*)((char*)d_ws + WB_OFF);

        int nprep = NB * TBLK + (2 * KR * 4 * 64 + 255) / 256;   // 2564 + 38
        prep_kernel<<<nprep, 256, 0, stream>>>(x, W, xt, Wf);

        if (ws_size >= WS_SPLIT) {
            bf16* P1 = (bf16*)((char*)d_ws + P1_OFF);
            conv_split_kernel<<<8 * NTILES, 256, 0, stream>>>(
                neigh, xt, Wf, bias, out, P1);
            reduce_kernel<<<2048, 256, 0, stream>>>(out, P1);
        } else {
            int nblk = 8 * ((NTILES + 1) / 2);   // 1288
            conv_nosplit_kernel<<<nblk, 256, 0, stream>>>(neigh, xt, Wf, bias, out);
        }
    } else {
        fallback_kernel<<<NB * NV, 64, 0, stream>>>(neigh, x, W, bias, out);
    }
}

// Round 7
// 194.052 us; speedup vs baseline: 1.3509x; 1.3509x over previous
//
#include <hip/hip_runtime.h>
#include <hip/hip_bf16.h>

// out[b,o,n] = sum_{k<19,c<64} x[b,c,neigh[n,k]] * W[o,k*64+c] + bias[o]
// B=4, N_VERTS=40962, K_RING=19, C=64.
//
// R15 = R14 with ONE change: gathers are normal cached loads again.
// R14's nt gathers bypassed L2 allocation -> the kc-split residency win
// (R13b: FETCH 23MB) was destroyed (FETCH 135MB), gathers hit L3 at
// ~400cyc and time scaled exactly with latency (83.6->130.9us, x1.56 ~
// 400/250): quantitative confirmation of the MSHR(~55 lines/CU) x
// latency model. R15 runs the INTENDED experiment: W out of the VMEM
// path (LDS-staged once per block, rings 16-18 in regs, zero recurring
// W stream) + L2-resident gathers. Model predicts conv ~55-65us; if it
// stays ~80-85, the wall is per-line request cost = gather roofline.

#define NV   40962
#define KR   19
#define CIN  64
#define COUT 64
#define NB   4
#define NTILES 321   // ceil(NV/128)
#define TBLK 641     // transpose blocks per batch (ceil(NV/64))

typedef __bf16 bf16;
typedef __bf16 bf16x8 __attribute__((ext_vector_type(8)));
typedef float  floatx4 __attribute__((ext_vector_type(4)));

#define XT_ELEMS ((size_t)NB * NV * CIN)               // also = NB*COUT*NV
#define WB_OFF   ((XT_ELEMS * 2 + 255) & ~(size_t)255)
#define WF_BYTES ((size_t)COUT * KR * CIN * 2)
#define P1_OFF   ((WB_OFF + WF_BYTES + 255) & ~(size_t)255)
#define WS_SPLIT (P1_OFF + XT_ELEMS * 2)               // ~42.1 MB
#define WS_MID   (WB_OFF + WF_BYTES)                   // ~21.2 MB

// ---------------------------------------------------------------------------
// prep_kernel: blocks [0, NB*TBLK) transpose x (B,C,N) fp32 ->
// xt2[b][kc][v][32ch] bf16 (64B line per vertex row); blocks
// [NB*TBLK, +38) convert W fp32 -> bf16 MFMA A-fragments, kc-major:
//   frag F = (kc*KR + ring)*4 + ot; lane L holds 8 bf16:
//   Wf[(F*64+L)*8 + j] = W[ot*16 + (L&15)][ring*64 + kc*32 + (L>>4)*8 + j]
// ---------------------------------------------------------------------------
__global__ __launch_bounds__(256) void prep_kernel(
    const float* __restrict__ x, const float* __restrict__ W,
    bf16* __restrict__ xt, bf16* __restrict__ Wf)
{
    __shared__ float tile[64 * 65];
    const int bid = blockIdx.x;
    const int t   = threadIdx.x;

    if (bid < NB * TBLK) {
        const int b  = bid / TBLK;
        const int v0 = (bid - b * TBLK) * 64;

        if (v0 + 64 <= NV) {
            #pragma unroll
            for (int r = 0; r < 4; ++r) {
                int flat = r * 256 + t;
                int c    = flat >> 4;
                int v4   = (flat & 15) * 4;
                floatx4 val = *(const floatx4*)&x[((size_t)(b * CIN + c)) * NV + v0 + v4];
                tile[(v4 + 0) * 65 + c] = val.x;
                tile[(v4 + 1) * 65 + c] = val.y;
                tile[(v4 + 2) * 65 + c] = val.z;
                tile[(v4 + 3) * 65 + c] = val.w;
            }
        } else {
            const int vl = t & 63;
            const int c0 = t >> 6;
            const int vg = min(v0 + vl, NV - 1);
            #pragma unroll
            for (int p = 0; p < 16; ++p) {
                int c = c0 * 16 + p;
                tile[vl * 65 + c] = x[((size_t)(b * CIN + c)) * NV + vg];
            }
        }
        __syncthreads();

        const int v = t >> 2;
        const int q = t & 3;
        if (v0 + v < NV) {
            #pragma unroll
            for (int p = 0; p < 2; ++p) {
                int chunk = q + p * 4;              // 8 channels
                bf16x8 o;
                #pragma unroll
                for (int j = 0; j < 8; ++j)
                    o[j] = (bf16)tile[v * 65 + chunk * 8 + j];
                int kc = chunk >> 2;
                size_t dst = ((size_t)((b * 2 + kc) * NV + v0 + v)) * 32 + (chunk & 3) * 8;
                __builtin_nontemporal_store(o, (bf16x8*)&xt[dst]);
            }
        }
    } else {
        const int idx = (bid - NB * TBLK) * 256 + t;
        if (idx < 2 * KR * 4 * 64) {
            const int lane = idx & 63;
            const int ot   = (idx >> 6) & 3;
            const int q    = idx >> 8;             // kc*KR + ring
            const int kc   = (q >= KR) ? 1 : 0;
            const int ring = q - kc * KR;
            const int row  = ot * 16 + (lane & 15);
            const int col0 = ring * 64 + kc * 32 + (lane >> 4) * 8;
            const float* src = W + (size_t)row * (KR * CIN) + col0;
            floatx4 a = *(const floatx4*)(src);
            floatx4 c = *(const floatx4*)(src + 4);
            bf16x8 o;
            o[0] = (bf16)a.x; o[1] = (bf16)a.y; o[2] = (bf16)a.z; o[3] = (bf16)a.w;
            o[4] = (bf16)c.x; o[5] = (bf16)c.y; o[6] = (bf16)c.z; o[7] = (bf16)c.w;
            *(bf16x8*)(Wf + (size_t)idx * 8) = o;
        }
    }
}

// ---------------------------------------------------------------------------
// conv_split_kernel: kc-split gather-GEMM, W in LDS.
// Block (b,kc,tile); slice = b*2+kc -> XCD (L2-resident 2.6MB xt slice).
// W rings 0..15 staged to LDS once (64KB, 2 blocks/CU); rings 16..18 in
// prologue-prefetched registers. Loop has NO barriers: per ring r, issue
// idx r+3 + gather r+2 (CACHED: L2-resident by construction), ds_read
// 4 W frags, 8 MFMA. Gathers are the only recurring VMEM.
// ---------------------------------------------------------------------------
__global__ __launch_bounds__(256, 2) void conv_split_kernel(
    const int*   __restrict__ neigh,
    const bf16*  __restrict__ xt,     // [b][kc][v][32] bf16
    const bf16*  __restrict__ Wf,     // kc-major fragments
    const float* __restrict__ bias,
    float*       __restrict__ out,    // (B, 64, NV) fp32
    bf16*        __restrict__ P1)     // (B, 64, NV) bf16 partial (kc=1)
{
    __shared__ bf16 Wl[16 * 2048];                 // 64KB: rings 0..15

    const int i     = blockIdx.x;
    const int slice = i & 7;                       // -> XCD
    const int b     = slice >> 1;
    const int kc    = slice & 1;
    const int tile  = i >> 3;                      // 0..320

    const int t    = threadIdx.x;
    const int wv   = t >> 6;
    const int lane = t & 63;
    const int l15  = lane & 15;
    const int g    = lane >> 4;

    const bf16* wsrc = Wf + (size_t)kc * (KR * 2048);   // elems

    // ---- stage W rings 0..15 -> LDS (once)
    #pragma unroll
    for (int ii = 0; ii < 16; ++ii) {
        int e = (ii * 256 + t) * 8;
        *(bf16x8*)&Wl[e] = *(const bf16x8*)&wsrc[e];
    }

    const int n0 = tile * 128 + wv * 32;
    int nn[2], ib[2];
    #pragma unroll
    for (int s = 0; s < 2; ++s) {
        nn[s] = n0 + s * 16 + l15;
        ib[s] = min(nn[s], NV - 1) * KR;
    }

    const bf16* xb = xt + ((size_t)slice * NV) * 32 + g * 8;   // + v*32

    floatx4 acc[2][4];
    #pragma unroll
    for (int s = 0; s < 2; ++s)
        #pragma unroll
        for (int o = 0; o < 4; ++o)
            acc[s][o] = (floatx4){0.f, 0.f, 0.f, 0.f};

    // ---- prologue: W rings 16..18 -> regs; idx rings 0,1,2; gathers 0,1
    bf16x8 wtail[3][4];
    #pragma unroll
    for (int rr = 0; rr < 3; ++rr)
        #pragma unroll
        for (int ot = 0; ot < 4; ++ot)
            wtail[rr][ot] = *(const bf16x8*)(wsrc + ((16 + rr) * 4 + ot) * 512 + lane * 8);

    int inxt[2], i3rd[2];
    bf16x8 xf[2], xg[2];
    #pragma unroll
    for (int s = 0; s < 2; ++s) {
        int v0i = neigh[ib[s] + 0];
        inxt[s] = neigh[ib[s] + 1];
        i3rd[s] = neigh[ib[s] + 2];
        int v = ((unsigned)v0i < (unsigned)NV) ? v0i : 0;
        xf[s] = *(const bf16x8*)(xb + (size_t)v * 32);
    }
    #pragma unroll
    for (int s = 0; s < 2; ++s) {
        int v = ((unsigned)inxt[s] < (unsigned)NV) ? inxt[s] : 0;
        xg[s] = *(const bf16x8*)(xb + (size_t)v * 32);
    }

    __syncthreads();   // one-time: W staging visible (drains prologue, ok)

    #pragma unroll
    for (int r = 0; r < KR; ++r) {
        int inew[2];
        bf16x8 xh[2];

        if (r + 3 < KR) {
            #pragma unroll
            for (int s = 0; s < 2; ++s)
                inew[s] = neigh[ib[s] + r + 3];
        }
        if (r + 2 < KR) {
            #pragma unroll
            for (int s = 0; s < 2; ++s) {
                int v = ((unsigned)i3rd[s] < (unsigned)NV) ? i3rd[s] : 0;
                xh[s] = *(const bf16x8*)(xb + (size_t)v * 32);
            }
        }

        // ---- W frags for ring r (LDS or tail regs; r is compile-time)
        bf16x8 wf[4];
        if (r < 16) {
            #pragma unroll
            for (int ot = 0; ot < 4; ++ot)
                wf[ot] = *(const bf16x8*)&Wl[(r * 4 + ot) * 512 + lane * 8];
        } else {
            #pragma unroll
            for (int ot = 0; ot < 4; ++ot)
                wf[ot] = wtail[r - 16][ot];
        }

        __builtin_amdgcn_s_setprio(1);
        #pragma unroll
        for (int ot = 0; ot < 4; ++ot)
            #pragma unroll
            for (int s = 0; s < 2; ++s)
                acc[s][ot] = __builtin_amdgcn_mfma_f32_16x16x32_bf16(
                    wf[ot], xf[s], acc[s][ot], 0, 0, 0);
        __builtin_amdgcn_s_setprio(0);

        // rotate (SSA-renamed under full unroll)
        if (r + 1 < KR) {
            #pragma unroll
            for (int s = 0; s < 2; ++s) xf[s] = xg[s];
        }
        if (r + 2 < KR) {
            #pragma unroll
            for (int s = 0; s < 2; ++s) {
                xg[s] = xh[s];
                inxt[s] = i3rd[s];
                i3rd[s] = (r + 3 < KR) ? inew[s] : 0;
            }
        }
    }

    // ---- epilogue: C/D col=l15 (vertex), row=g*4+ii (output)
    if (kc == 0) {
        #pragma unroll
        for (int ot = 0; ot < 4; ++ot) {
            #pragma unroll
            for (int ii = 0; ii < 4; ++ii) {
                const int o = ot * 16 + g * 4 + ii;
                const float bv = bias[o];
                #pragma unroll
                for (int s = 0; s < 2; ++s) {
                    if (nn[s] < NV)
                        __builtin_nontemporal_store(acc[s][ot][ii] + bv,
                            &out[((size_t)(b * COUT + o)) * NV + nn[s]]);
                }
            }
        }
    } else {
        #pragma unroll
        for (int ot = 0; ot < 4; ++ot) {
            #pragma unroll
            for (int ii = 0; ii < 4; ++ii) {
                const int o = ot * 16 + g * 4 + ii;
                #pragma unroll
                for (int s = 0; s < 2; ++s) {
                    if (nn[s] < NV)
                        __builtin_nontemporal_store((bf16)acc[s][ot][ii],
                            &P1[((size_t)(b * COUT + o)) * NV + nn[s]]);
                }
            }
        }
    }
}

// ---------------------------------------------------------------------------
// reduce_kernel: out += P1 (bf16). Pure streaming, nt.
// ---------------------------------------------------------------------------
__global__ __launch_bounds__(256) void reduce_kernel(
    float* __restrict__ out, const bf16* __restrict__ P1)
{
    const size_t total8 = XT_ELEMS / 8;
    for (size_t j = (size_t)blockIdx.x * 256 + threadIdx.x; j < total8;
         j += (size_t)gridDim.x * 256) {
        bf16x8 p = __builtin_nontemporal_load((const bf16x8*)P1 + j);
        floatx4* op = (floatx4*)out + j * 2;
        floatx4 a = __builtin_nontemporal_load(op);
        floatx4 c = __builtin_nontemporal_load(op + 1);
        a.x += (float)p[0]; a.y += (float)p[1]; a.z += (float)p[2]; a.w += (float)p[3];
        c.x += (float)p[4]; c.y += (float)p[5]; c.z += (float)p[6]; c.w += (float)p[7];
        __builtin_nontemporal_store(a, op);
        __builtin_nontemporal_store(c, op + 1);
    }
}

// ---------------------------------------------------------------------------
// Mid fallback (ws fits old budget only): both kc in-block, direct out.
// ---------------------------------------------------------------------------
__global__ __launch_bounds__(256, 3) void conv_nosplit_kernel(
    const int*   __restrict__ neigh,
    const bf16*  __restrict__ xt,
    const bf16*  __restrict__ Wf,
    const float* __restrict__ bias,
    float*       __restrict__ out)
{
    const int i    = blockIdx.x;
    const int b    = (i & 7) >> 1;
    const int tile = (i >> 3) * 2 + (i & 1);
    if (tile >= NTILES) return;

    const int t    = threadIdx.x;
    const int wv   = t >> 6;
    const int lane = t & 63;
    const int l15  = lane & 15;
    const int g    = lane >> 4;

    const int n0 = tile * 128 + wv * 32;
    int nn[2], ib[2];
    #pragma unroll
    for (int s = 0; s < 2; ++s) {
        nn[s] = n0 + s * 16 + l15;
        ib[s] = min(nn[s], NV - 1) * KR;
    }

    const bf16* xb0 = xt + ((size_t)(b * 2 + 0) * NV) * 32 + g * 8;
    const bf16* xb1 = xt + ((size_t)(b * 2 + 1) * NV) * 32 + g * 8;
    const bf16* wb  = Wf + lane * 8;

    floatx4 acc[2][4];
    #pragma unroll
    for (int s = 0; s < 2; ++s)
        #pragma unroll
        for (int o = 0; o < 4; ++o)
            acc[s][o] = (floatx4){0.f, 0.f, 0.f, 0.f};

    int inxt[2];
    bf16x8 xf[2][2], wf[2][4];
    #pragma unroll
    for (int s = 0; s < 2; ++s) {
        int v0i = neigh[ib[s] + 0];
        inxt[s] = neigh[ib[s] + 1];
        int v = ((unsigned)v0i < (unsigned)NV) ? v0i : 0;
        xf[s][0] = *(const bf16x8*)(xb0 + (size_t)v * 32);
        xf[s][1] = *(const bf16x8*)(xb1 + (size_t)v * 32);
    }
    #pragma unroll
    for (int kc = 0; kc < 2; ++kc)
        #pragma unroll
        for (int f = 0; f < 4; ++f)
            wf[kc][f] = *(const bf16x8*)(wb + (size_t)kc * (KR * 2048) + f * 512);

    #pragma unroll
    for (int r = 0; r < KR; ++r) {
        int inew[2];
        bf16x8 wg[2][4], xg[2][2];
        if (r + 2 < KR) {
            #pragma unroll
            for (int s = 0; s < 2; ++s) inew[s] = neigh[ib[s] + r + 2];
        }
        if (r + 1 < KR) {
            #pragma unroll
            for (int kc = 0; kc < 2; ++kc)
                #pragma unroll
                for (int f = 0; f < 4; ++f)
                    wg[kc][f] = *(const bf16x8*)(wb + (size_t)kc * (KR * 2048)
                                                 + (size_t)(r + 1) * 2048 + f * 512);
            #pragma unroll
            for (int s = 0; s < 2; ++s) {
                int v = ((unsigned)inxt[s] < (unsigned)NV) ? inxt[s] : 0;
                xg[s][0] = *(const bf16x8*)(xb0 + (size_t)v * 32);
                xg[s][1] = *(const bf16x8*)(xb1 + (size_t)v * 32);
            }
        }

        __builtin_amdgcn_s_setprio(1);
        #pragma unroll
        for (int kc = 0; kc < 2; ++kc)
            #pragma unroll
            for (int ot = 0; ot < 4; ++ot)
                #pragma unroll
                for (int s = 0; s < 2; ++s)
                    acc[s][ot] = __builtin_amdgcn_mfma_f32_16x16x32_bf16(
                        wf[kc][ot], xf[s][kc], acc[s][ot], 0, 0, 0);
        __builtin_amdgcn_s_setprio(0);

        if (r + 1 < KR) {
            #pragma unroll
            for (int s = 0; s < 2; ++s) {
                xf[s][0] = xg[s][0];
                xf[s][1] = xg[s][1];
                inxt[s]  = (r + 2 < KR) ? inew[s] : 0;
            }
            #pragma unroll
            for (int kc = 0; kc < 2; ++kc)
                #pragma unroll
                for (int f = 0; f < 4; ++f)
                    wf[kc][f] = wg[kc][f];
        }
    }

    #pragma unroll
    for (int ot = 0; ot < 4; ++ot) {
        #pragma unroll
        for (int ii = 0; ii < 4; ++ii) {
            const int o = ot * 16 + g * 4 + ii;
            const float bv = bias[o];
            #pragma unroll
            for (int s = 0; s < 2; ++s) {
                if (nn[s] < NV)
                    out[((size_t)(b * COUT + o)) * NV + nn[s]] = acc[s][ot][ii] + bv;
            }
        }
    }
}

// ---------------------------------------------------------------------------
// Last-resort fallback (no workspace).
// ---------------------------------------------------------------------------
__global__ __launch_bounds__(64) void fallback_kernel(
    const int*   __restrict__ neigh,
    const float* __restrict__ x,
    const float* __restrict__ W,
    const float* __restrict__ bias,
    float*       __restrict__ out)
{
    __shared__ float xg[KR * CIN];
    const int bn = blockIdx.x;
    const int b  = bn / NV;
    const int n  = bn % NV;
    const int t  = threadIdx.x;

    for (int k = t; k < KR * CIN; k += 64) {
        int r = k / CIN, c = k - r * CIN;
        int v = neigh[n * KR + r];
        v = ((unsigned)v < (unsigned)NV) ? v : 0;
        xg[k] = x[((size_t)(b * CIN + c)) * NV + v];
    }
    __syncthreads();

    float s = bias[t];
    const float* wrow = W + (size_t)t * (KR * CIN);
    for (int k = 0; k < KR * CIN; ++k) s += xg[k] * wrow[k];
    out[((size_t)(b * COUT + t)) * NV + n] = s;
}

// ---------------------------------------------------------------------------
extern "C" void kernel_launch(void* const* d_in, const int* in_sizes, int n_in,
                              void* d_out, int out_size, void* d_ws, size_t ws_size,
                              hipStream_t stream)
{
    const float* x     = (const float*)d_in[0];
    const int*   neigh = (const int*)d_in[1];
    const float* W     = (const float*)d_in[2];
    const float* bias  = (const float*)d_in[3];
    float* out = (float*)d_out;

    if (d_ws != nullptr && ws_size >= WS_MID) {
        bf16* xt = (bf16*)d_ws;
        bf16* Wf = (bf16*)((char*)d_ws + WB_OFF);

        int nprep = NB * TBLK + (2 * KR * 4 * 64 + 255) / 256;   // 2564 + 38
        prep_kernel<<<nprep, 256, 0, stream>>>(x, W, xt, Wf);

        if (ws_size >= WS_SPLIT) {
            bf16* P1 = (bf16*)((char*)d_ws + P1_OFF);
            conv_split_kernel<<<8 * NTILES, 256, 0, stream>>>(
                neigh, xt, Wf, bias, out, P1);
            reduce_kernel<<<2048, 256, 0, stream>>>(out, P1);
        } else {
            int nblk = 8 * ((NTILES + 1) / 2);   // 1288
            conv_nosplit_kernel<<<nblk, 256, 0, stream>>>(neigh, xt, Wf, bias, out);
        }
    } else {
        fallback_kernel<<<NB * NV, 64, 0, stream>>>(neigh, x, W, bias, out);
    }
}

// Round 8
// 168.677 us; speedup vs baseline: 1.5541x; 1.1504x over previous
//
#include <hip/hip_runtime.h>
#include <hip/hip_bf16.h>

// out[b,o,n] = sum_{k<19,c<64} x[b,c,neigh[n,k]] * W[o,k*64+c] + bias[o]
// B=4, N_VERTS=40962, K_RING=19, C=64. Storage: x,W,b,out fp32 (values
// bf16-representable), neigh int32. bf16 MFMA path near-exact (1.6e-2).
//
// R16 = revert to R9, the empirical optimum. Rounds 10-15 established:
// conv is pinned at ~0.12 64B-line-requests/cyc/CU (TCP-MSHR ~30 x
// L2-hit latency ~250cyc; equivalently ~4 req/cyc/XCD at L2) across SIX
// structures (78-85us): barriers vs none, W in LDS vs global vs regs,
// L2-resident kc-split (FETCH 105->23MB, time unchanged) vs not,
// occupancy 18-35%. Gather lines are structural: B*NV*KR*128B / 64B =
// 6.23M -> floor ~78-81us; R9 sits on it. nt-gathers bypass L2 and cost
// +56% (R14) - never do that. The kc-split + reduce pass adds ~20us of
// pure streaming. Rest of dur_us ~85us is harness-fixed (reset/restore
// dispatches) + prep ~6us. Only fp8 (half the lines) could beat the
// wall; expected absmax ~10x current 0.0156 - rejected on correctness.

#define NV   40962
#define KR   19
#define CIN  64
#define COUT 64
#define NB   4
#define NTILES 321   // ceil(NV/128)

typedef __bf16 bf16;
typedef __bf16 bf16x8 __attribute__((ext_vector_type(8)));
typedef float  floatx4 __attribute__((ext_vector_type(4)));

#define XT_ELEMS ((size_t)NB * NV * CIN)
#define WB_OFF   ((XT_ELEMS * 2 + 255) & ~(size_t)255)
#define WS_NEED  (WB_OFF + (size_t)COUT * KR * CIN * 2)

// ---------------------------------------------------------------------------
// Kernel 1: x (B,C,N) fp32 -> xt (B,N,64) bf16 (row per vertex = 128B line).
// ---------------------------------------------------------------------------
__global__ __launch_bounds__(256) void transpose_kernel(
    const float* __restrict__ x, bf16* __restrict__ xt)
{
    __shared__ float tile[64 * 65];
    const int b  = blockIdx.y;
    const int v0 = blockIdx.x * 64;
    const int t  = threadIdx.x;

    const int vl = t & 63;
    const int c0 = t >> 6;
    const int vg = min(v0 + vl, NV - 1);
    #pragma unroll
    for (int p = 0; p < 16; ++p) {
        int c = c0 * 16 + p;
        tile[vl * 65 + c] = x[((size_t)(b * CIN + c)) * NV + vg];
    }
    __syncthreads();

    const int v = t >> 2;
    const int q = t & 3;
    if (v0 + v < NV) {
        #pragma unroll
        for (int p = 0; p < 2; ++p) {
            int chunk = q + p * 4;
            bf16x8 o;
            #pragma unroll
            for (int j = 0; j < 8; ++j)
                o[j] = (bf16)tile[v * 65 + chunk * 8 + j];
            *(bf16x8*)&xt[((size_t)(b * NV + v0 + v)) * 64 + chunk * 8] = o;
        }
    }
}

// ---------------------------------------------------------------------------
// Kernel 1b: W fp32 (64x1216) -> bf16 (152 KB, once)
// ---------------------------------------------------------------------------
__global__ __launch_bounds__(256) void convw_kernel(
    const float* __restrict__ W, bf16* __restrict__ Wb)
{
    int i = blockIdx.x * 256 + threadIdx.x;
    const int total4 = COUT * KR * CIN / 4;
    if (i < total4) {
        float4 v = ((const float4*)W)[i];
        bf16* p = Wb + (size_t)i * 4;
        p[0] = (bf16)v.x; p[1] = (bf16)v.y; p[2] = (bf16)v.z; p[3] = (bf16)v.w;
    }
}

// ---------------------------------------------------------------------------
// Kernel 2: gather-GEMM, mfma_f32_16x16x32_bf16, ring-pair pipelined.
// W LDS layout: slot(ot,kc,g,l15) at elem ((ot*2+kc)*64 + g*16 + l15)*8
//  -> MFMA read for (ot,kc) is base + lane*16B : conflict-free, one addr reg.
// Staging: thread (row=t>>2, q=t&3) loads W[row, ring*64 + q*16 .. +15]
// (two bf16x8) -> slots (q>>1, (q&1)*2) and (q>>1, (q&1)*2+1). 512 slots,
// each written exactly once.
// ---------------------------------------------------------------------------
__global__ __launch_bounds__(256, 4) void conv_kernel(
    const int*   __restrict__ neigh,
    const bf16*  __restrict__ xt,
    const bf16*  __restrict__ Wb,     // (64, 1216) bf16
    const float* __restrict__ bias,   // (64,) fp32
    float*       __restrict__ out)    // (B, 64, NV) fp32
{
    __shared__ alignas(16) bf16 Wlds[2][2][4096];   // [stage][ring-in-pair]

    const int i    = blockIdx.x;
    const int b    = (i & 7) >> 1;                  // XCD pair -> batch
    const int tile = (i >> 3) * 2 + (i & 1);
    if (tile >= NTILES) return;
    const int n0   = tile * 128;

    const int t    = threadIdx.x;
    const int wv   = t >> 6;
    const int lane = t & 63;
    const int l15  = lane & 15;
    const int g    = lane >> 4;

    int nn[2], ib[2];
    #pragma unroll
    for (int s = 0; s < 2; ++s) {
        nn[s] = n0 + wv * 32 + s * 16 + l15;
        ib[s] = min(nn[s], NV - 1) * KR;
    }

    const bf16* xb = xt + (((size_t)b * NV) << 6) + g * 8;   // + (v<<6)

    // W staging decomposition: thread -> (row, quarter)
    const int srow = t >> 2;            // o row 0..63
    const int c4   = t & 3;             // 16-elem quarter of the 64-elem slice
    const int skc  = c4 >> 1;
    const int sg0  = (c4 & 1) * 2;
    const int sot  = srow >> 4, sl15 = srow & 15;
    const int sdst0 = ((sot * 2 + skc) * 64 + (sg0 + 0) * 16 + sl15) * 8;
    const int sdst1 = ((sot * 2 + skc) * 64 + (sg0 + 1) * 16 + sl15) * 8;
    const bf16* sw = Wb + (size_t)srow * (KR * 64) + c4 * 16;

    floatx4 acc[2][4];
    #pragma unroll
    for (int s = 0; s < 2; ++s)
        #pragma unroll
        for (int o = 0; o < 4; ++o)
            acc[s][o] = (floatx4){0.f, 0.f, 0.f, 0.f};

    bf16x8 xf[2][2][2];   // [ring-in-pair][s][half] : current pair
    bf16x8 xg[2][2][2];   // next pair

    // ---- prologue: stage pair 0 (rings 0,1) -> buf 0; gather rings 0,1
    #pragma unroll
    for (int j = 0; j < 2; ++j) {
        bf16x8 w0 = *(const bf16x8*)(sw + j * 64);
        bf16x8 w1 = *(const bf16x8*)(sw + j * 64 + 8);
        *(bf16x8*)(&Wlds[0][j][sdst0]) = w0;
        *(bf16x8*)(&Wlds[0][j][sdst1]) = w1;
        #pragma unroll
        for (int s = 0; s < 2; ++s) {
            int v = neigh[ib[s] + j];
            v = ((unsigned)v < (unsigned)NV) ? v : 0;
            const bf16* p = xb + ((size_t)v << 6);
            xf[j][s][0] = *(const bf16x8*)(p);
            xf[j][s][1] = *(const bf16x8*)(p + 32);
        }
    }
    __syncthreads();

    #pragma unroll
    for (int rp = 0; rp < 10; ++rp) {           // pairs: rings (2rp, 2rp+1)
        const int st = rp & 1;

        // ---- prefetch next pair: W -> buf st^1, gathers -> xg
        if (rp + 1 < 10) {
            #pragma unroll
            for (int j = 0; j < 2; ++j) {
                const int ring = 2 * (rp + 1) + j;
                if (ring < KR) {
                    bf16x8 w0 = *(const bf16x8*)(sw + ring * 64);
                    bf16x8 w1 = *(const bf16x8*)(sw + ring * 64 + 8);
                    *(bf16x8*)(&Wlds[st ^ 1][j][sdst0]) = w0;
                    *(bf16x8*)(&Wlds[st ^ 1][j][sdst1]) = w1;
                    #pragma unroll
                    for (int s = 0; s < 2; ++s) {
                        int v = neigh[ib[s] + ring];
                        v = ((unsigned)v < (unsigned)NV) ? v : 0;
                        const bf16* p = xb + ((size_t)v << 6);
                        xg[j][s][0] = *(const bf16x8*)(p);
                        xg[j][s][1] = *(const bf16x8*)(p + 32);
                    }
                }
            }
        }

        // ---- compute rings 2rp, 2rp+1 from buf st
        #pragma unroll
        for (int j = 0; j < 2; ++j) {
            const int ring = 2 * rp + j;
            if (ring < KR) {
                const bf16* wbase = &Wlds[st][j][lane * 8];
                #pragma unroll
                for (int ot = 0; ot < 4; ++ot) {
                    #pragma unroll
                    for (int kc = 0; kc < 2; ++kc) {
                        bf16x8 wf = *(const bf16x8*)(wbase + (ot * 2 + kc) * 512);
                        #pragma unroll
                        for (int s = 0; s < 2; ++s) {
                            acc[s][ot] = __builtin_amdgcn_mfma_f32_16x16x32_bf16(
                                wf, xf[j][s][kc], acc[s][ot], 0, 0, 0);
                        }
                    }
                }
            }
        }
        __syncthreads();

        // rotate gather pipeline (SSA-renamed under full unroll)
        #pragma unroll
        for (int j = 0; j < 2; ++j)
            #pragma unroll
            for (int s = 0; s < 2; ++s) {
                xf[j][s][0] = xg[j][s][0];
                xf[j][s][1] = xg[j][s][1];
            }
    }

    #pragma unroll
    for (int ot = 0; ot < 4; ++ot) {
        #pragma unroll
        for (int ii = 0; ii < 4; ++ii) {
            int o = ot * 16 + g * 4 + ii;
            float bv = bias[o];
            #pragma unroll
            for (int s = 0; s < 2; ++s) {
                if (nn[s] < NV) {
                    out[((size_t)(b * COUT + o)) * NV + nn[s]] =
                        acc[s][ot][ii] + bv;
                }
            }
        }
    }
}

// ---------------------------------------------------------------------------
// Fallback (no workspace): one block per (b,n); fp32 in/out.
// ---------------------------------------------------------------------------
__global__ __launch_bounds__(64) void fallback_kernel(
    const int*   __restrict__ neigh,
    const float* __restrict__ x,
    const float* __restrict__ W,
    const float* __restrict__ bias,
    float*       __restrict__ out)
{
    __shared__ float xg[KR * CIN];
    const int bn = blockIdx.x;
    const int b  = bn / NV;
    const int n  = bn % NV;
    const int t  = threadIdx.x;

    for (int k = t; k < KR * CIN; k += 64) {
        int r = k / CIN, c = k - r * CIN;
        int v = neigh[n * KR + r];
        v = ((unsigned)v < (unsigned)NV) ? v : 0;
        xg[k] = x[((size_t)(b * CIN + c)) * NV + v];
    }
    __syncthreads();

    float s = bias[t];
    const float* wrow = W + (size_t)t * (KR * CIN);
    for (int k = 0; k < KR * CIN; ++k) s += xg[k] * wrow[k];
    out[((size_t)(b * COUT + t)) * NV + n] = s;
}

// ---------------------------------------------------------------------------
extern "C" void kernel_launch(void* const* d_in, const int* in_sizes, int n_in,
                              void* d_out, int out_size, void* d_ws, size_t ws_size,
                              hipStream_t stream)
{
    const float* x     = (const float*)d_in[0];
    const int*   neigh = (const int*)d_in[1];
    const float* W     = (const float*)d_in[2];
    const float* bias  = (const float*)d_in[3];
    float* out = (float*)d_out;

    if (d_ws != nullptr && ws_size >= WS_NEED) {
        bf16* xt = (bf16*)d_ws;
        bf16* Wb = (bf16*)((char*)d_ws + WB_OFF);

        dim3 tgrid((NV + 63) / 64, NB);
        transpose_kernel<<<tgrid, 256, 0, stream>>>(x, xt);
        convw_kernel<<<(COUT * KR * CIN / 4 + 255) / 256, 256, 0, stream>>>(W, Wb);

        int nblk = 8 * ((NTILES + 1) / 2);          // 1288
        conv_kernel<<<nblk, 256, 0, stream>>>(neigh, xt, Wb, bias, out);
    } else {
        fallback_kernel<<<NB * NV, 64, 0, stream>>>(neigh, x, W, bias, out);
    }
}